// Round 4
// baseline (725.942 us; speedup 1.0000x reference)
//
#include <hip/hip_runtime.h>
#include <hip/hip_bf16.h>
#include <math.h>

#define L_LEN 110592   // 48*48*48
#define TILE 32
#define NT 3456        // tiles per batch
#define STRX 72        // staged-x LDS row stride (bf16)
#define STRC 136       // conv-out LDS row stride (bf16)
#define STRS 40        // sbuf col stride (bf16)
#define RESS 132       // resf row stride (f32)

typedef float  floatx4 __attribute__((ext_vector_type(4)));
typedef short  short8  __attribute__((ext_vector_type(8)));
typedef short  short4v __attribute__((ext_vector_type(4)));

__device__ __forceinline__ float fast_silu(float v) {
    return v * __builtin_amdgcn_rcpf(1.f + __expf(-v));
}
__device__ __forceinline__ float fast_softplus(float d) {
    return fmaxf(d, 0.f) + __logf(1.f + __expf(-fabsf(d)));
}
__device__ __forceinline__ short f2bf(float f) {
    __hip_bfloat16 h = __float2bfloat16(f);
    return *reinterpret_cast<short*>(&h);
}
__device__ __forceinline__ float bf2f(short s) {
    __hip_bfloat16 h = *reinterpret_cast<__hip_bfloat16*>(&s);
    return __bfloat162float(h);
}
__device__ __forceinline__ short8 pack_bf8(float4 a, float4 b) {
    short8 r;
    r[0] = f2bf(a.x); r[1] = f2bf(a.y); r[2] = f2bf(a.z); r[3] = f2bf(a.w);
    r[4] = f2bf(b.x); r[5] = f2bf(b.y); r[6] = f2bf(b.z); r[7] = f2bf(b.w);
    return r;
}

// ---------------------------------------------------------------------------
// kW_w: transposed bf16 weight copies + zero the lookback flags.
// ---------------------------------------------------------------------------
__global__ __launch_bounds__(256) void kW_w(
    const float* __restrict__ W_in, const float* __restrict__ W_x,
    const float* __restrict__ W_dt, const float* __restrict__ W_out,
    __hip_bfloat16* __restrict__ wti, __hip_bfloat16* __restrict__ wpt,
    __hip_bfloat16* __restrict__ wtr, __hip_bfloat16* __restrict__ wot,
    int* __restrict__ flags)
{
    const int t = threadIdx.x;
    for (int idx = t; idx < 128 * 64; idx += 256) {
        int n = idx >> 6, k = idx & 63;
        wti[idx] = __float2bfloat16(W_in[k * 256 + n]);
        wtr[idx] = __float2bfloat16(W_in[k * 256 + 128 + n]);
    }
    for (int idx = t; idx < 256 * 128; idx += 256) {
        int n = idx >> 7, k = idx & 127;
        float v = (n < 128) ? W_x[k * 144 + n] : W_dt[k * 128 + (n - 128)];
        wpt[idx] = __float2bfloat16(v);
    }
    for (int idx = t; idx < 64 * 128; idx += 256) {
        int n = idx >> 7, k = idx & 127;
        wot[idx] = __float2bfloat16(W_out[k * 64 + n]);
    }
    for (int idx = t; idx < 2 * NT; idx += 256) flags[idx] = 0;
}

// ---------------------------------------------------------------------------
// kF: fully fused block. Per tile (32 rows):
//  stage x -> in-proj MFMA + conv-in-regs + silu -> proj MFMAs -> s-tile in
//  LDS + channel aggregates -> publish agg (flag=1) -> res-proj MFMA ->
//  in-tile scan -> decoupled lookback (wave 0, window=64) -> publish
//  inclusive prefix (flag=2) -> gate -> out-proj MFMA -> residual + LN.
// Relies on ascending workgroup dispatch order (rocPRIM lookback assumption).
// Cross-XCD visibility: agent-scope atomics (payload relaxed, flag rel/acq).
// ---------------------------------------------------------------------------
__global__ __launch_bounds__(256, 4) void kF(
    const float* __restrict__ x,
    const __hip_bfloat16* __restrict__ wti,
    const __hip_bfloat16* __restrict__ wpt,
    const __hip_bfloat16* __restrict__ wtr,
    const __hip_bfloat16* __restrict__ wot,
    const float* __restrict__ conv_w, const float* __restrict__ conv_b,
    const float* __restrict__ b_dt,
    const float* __restrict__ gamma, const float* __restrict__ beta,
    float* __restrict__ agg, float* __restrict__ pref,
    int* __restrict__ flags, float* __restrict__ out)
{
    // LDS pool, 35584 B -> 4 blocks/CU.
    //   xbf  [0,6912)        48x72 bf16, live whole kernel
    //   xcb  [6912,15616)    32x136 bf16 (phase1->2)
    //   sbuf [6912,17152)    128x40 bf16 (phase2->scan), overlays xcb
    //   ybf  [6912,15616)    32x136 bf16 (gate->out-proj), overlays sbuf
    //   resf [17152,34048)   32x132 f32; reused as zbuf 32x68 f32
    //   totb [34048,35072)   256 f32; reused as offb[128]
    //   aggb [35072,35584)   128 f32
    __shared__ __align__(16) char pool[35584];
    __hip_bfloat16* const xbf  = (__hip_bfloat16*)pool;
    __hip_bfloat16* const xcb  = (__hip_bfloat16*)(pool + 6912);
    __hip_bfloat16* const sbuf = (__hip_bfloat16*)(pool + 6912);
    __hip_bfloat16* const ybf  = (__hip_bfloat16*)(pool + 6912);
    float* const resf = (float*)(pool + 17152);
    float* const totb = (float*)(pool + 34048);
    float* const offb = totb;
    float* const aggb = (float*)(pool + 35072);

    const int t = threadIdx.x;
    const int lane = t & 63;
    const int w = t >> 6;
    const int quad = lane >> 4;
    const int lr = lane & 15;
    const int tile = blockIdx.x;
    const int b = blockIdx.y;
    const int l0 = tile * TILE;
    const long base = (long)b * L_LEN;
    const long cb = (long)b * NT;

    // ---- stage: x rows l0-1 .. l0+46 -> bf16 LDS
    for (int idx = t; idx < 384; idx += 256) {
        const int row = idx >> 3, c8 = (idx & 7) << 3;
        const long gr = (long)l0 - 1 + row;
        float4 u0 = {0.f, 0.f, 0.f, 0.f}, u1 = {0.f, 0.f, 0.f, 0.f};
        if (gr >= 0 && gr < L_LEN) {
            const float* xp = x + ((base + gr) << 6) + c8;
            u0 = ((const float4*)xp)[0];
            u1 = ((const float4*)xp)[1];
        }
        *(short8*)&xbf[row * STRX + c8] = pack_bf8(u0, u1);
    }
    __syncthreads();

    // ---- phase 1: in-proj (M=48,N=128,K=64) + depthwise conv(4) + silu
    {
        floatx4 acc[3][2] = {};
        #pragma unroll
        for (int ks = 0; ks < 2; ++ks) {
            short8 bfr0 = *(const short8*)(wti + ((w * 32 + lr) << 6) + ks * 32 + quad * 8);
            short8 bfr1 = *(const short8*)(wti + ((w * 32 + 16 + lr) << 6) + ks * 32 + quad * 8);
            #pragma unroll
            for (int mt = 0; mt < 3; ++mt) {
                short8 afr = *(const short8*)&xbf[(mt * 16 + lr) * STRX + ks * 32 + quad * 8];
                acc[mt][0] = __builtin_amdgcn_mfma_f32_16x16x32_bf16(afr, bfr0, acc[mt][0], 0, 0, 0);
                acc[mt][1] = __builtin_amdgcn_mfma_f32_16x16x32_bf16(afr, bfr1, acc[mt][1], 0, 0, 0);
            }
        }
        const int srcLane = (((quad + 1) & 3) << 4) | lr;
        #pragma unroll
        for (int jj = 0; jj < 2; ++jj) {
            const int col = w * 32 + jj * 16 + lr;
            const float cw0 = conv_w[col],       cw1 = conv_w[128 + col];
            const float cw2 = conv_w[256 + col], cw3 = conv_w[384 + col];
            const float cbv = conv_b[col];
            #pragma unroll
            for (int m = 0; m < 2; ++m) {
                float s0 = (quad == 0) ? acc[m + 1][jj][0] : acc[m][jj][0];
                float s1 = (quad == 0) ? acc[m + 1][jj][1] : acc[m][jj][1];
                float s2 = (quad == 0) ? acc[m + 1][jj][2] : acc[m][jj][2];
                const float e0 = __shfl(s0, srcLane);
                const float e1 = __shfl(s1, srcLane);
                const float e2 = __shfl(s2, srcLane);
                const float a0 = acc[m][jj][0], a1 = acc[m][jj][1];
                const float a2 = acc[m][jj][2], a3 = acc[m][jj][3];
                const int rb = m * 16 + quad * 4;
                xcb[(rb + 0) * STRC + col] =
                    __float2bfloat16(fast_silu(cbv + cw0 * a0 + cw1 * a1 + cw2 * a2 + cw3 * a3));
                xcb[(rb + 1) * STRC + col] =
                    __float2bfloat16(fast_silu(cbv + cw0 * a1 + cw1 * a2 + cw2 * a3 + cw3 * e0));
                xcb[(rb + 2) * STRC + col] =
                    __float2bfloat16(fast_silu(cbv + cw0 * a2 + cw1 * a3 + cw2 * e0 + cw3 * e1));
                xcb[(rb + 3) * STRC + col] =
                    __float2bfloat16(fast_silu(cbv + cw0 * a3 + cw1 * e0 + cw2 * e1 + cw3 * e2));
            }
        }
    }
    __syncthreads();

    // ---- phase 2: proj MFMAs -> s-tile (LDS) + channel aggregates, publish
    {
        floatx4 accx[2][2] = {}, accd[2][2] = {};
        #pragma unroll
        for (int ks = 0; ks < 4; ++ks) {
            short8 afr[2];
            #pragma unroll
            for (int mt = 0; mt < 2; ++mt)
                afr[mt] = *(const short8*)&xcb[(mt * 16 + lr) * STRC + ks * 32 + quad * 8];
            #pragma unroll
            for (int j = 0; j < 2; ++j) {
                const int n = w * 32 + j * 16 + lr;
                short8 bx = *(const short8*)(wpt + (n << 7) + ks * 32 + quad * 8);
                short8 bd = *(const short8*)(wpt + ((n + 128) << 7) + ks * 32 + quad * 8);
                #pragma unroll
                for (int mt = 0; mt < 2; ++mt) {
                    accx[mt][j] = __builtin_amdgcn_mfma_f32_16x16x32_bf16(afr[mt], bx, accx[mt][j], 0, 0, 0);
                    accd[mt][j] = __builtin_amdgcn_mfma_f32_16x16x32_bf16(afr[mt], bd, accd[mt][j], 0, 0, 0);
                }
            }
        }
        __syncthreads();   // xcb reads done; sbuf may overwrite

        float ps0 = 0.f, ps1 = 0.f;
        #pragma unroll
        for (int j = 0; j < 2; ++j) {
            const int col = w * 32 + j * 16 + lr;
            const float bdv = b_dt[col];
            float psl = 0.f;
            #pragma unroll
            for (int mt = 0; mt < 2; ++mt) {
                short4v pk;
                #pragma unroll
                for (int r = 0; r < 4; ++r) {
                    float dv = accd[mt][j][r] + bdv;
                    float sv = accx[mt][j][r] * fast_softplus(dv);
                    short h = f2bf(sv);
                    pk[r] = h;
                    psl += bf2f(h);
                }
                *(short4v*)&sbuf[col * STRS + quad * 4 + mt * 16] = pk;
            }
            if (j == 0) ps0 = psl; else ps1 = psl;
        }
        ps0 += __shfl_xor(ps0, 16); ps0 += __shfl_xor(ps0, 32);
        ps1 += __shfl_xor(ps1, 16); ps1 += __shfl_xor(ps1, 32);
        const long mb = (cb + tile) << 7;
        if (quad == 0) {
            const int col = w * 32 + lr;
            aggb[col] = ps0;
            __hip_atomic_store(&agg[mb + col], ps0, __ATOMIC_RELAXED, __HIP_MEMORY_SCOPE_AGENT);
        } else if (quad == 1) {
            const int col = w * 32 + 16 + lr;
            aggb[col] = ps1;
            __hip_atomic_store(&agg[mb + col], ps1, __ATOMIC_RELAXED, __HIP_MEMORY_SCOPE_AGENT);
        }
        __syncthreads();   // sbuf + aggb + agg stores drained (per-wave vmcnt)
        if (t == 0)
            __hip_atomic_store(&flags[cb + tile], 1, __ATOMIC_RELEASE, __HIP_MEMORY_SCOPE_AGENT);
    }

    // ---- phase 3: res-proj MFMA (M=32, rows l0..l0+31 = xbf rows 1..32),
    //      silu -> resf. Overlaps predecessors' agg publishing.
    {
        floatx4 acc[2][2] = {};
        #pragma unroll
        for (int ks = 0; ks < 2; ++ks) {
            short8 bfr0 = *(const short8*)(wtr + ((w * 32 + lr) << 6) + ks * 32 + quad * 8);
            short8 bfr1 = *(const short8*)(wtr + ((w * 32 + 16 + lr) << 6) + ks * 32 + quad * 8);
            #pragma unroll
            for (int mt = 0; mt < 2; ++mt) {
                short8 afr = *(const short8*)&xbf[(1 + mt * 16 + lr) * STRX + ks * 32 + quad * 8];
                acc[mt][0] = __builtin_amdgcn_mfma_f32_16x16x32_bf16(afr, bfr0, acc[mt][0], 0, 0, 0);
                acc[mt][1] = __builtin_amdgcn_mfma_f32_16x16x32_bf16(afr, bfr1, acc[mt][1], 0, 0, 0);
            }
        }
        #pragma unroll
        for (int mt = 0; mt < 2; ++mt)
            #pragma unroll
            for (int j = 0; j < 2; ++j) {
                const int col = w * 32 + j * 16 + lr;
                #pragma unroll
                for (int r = 0; r < 4; ++r)
                    resf[(mt * 16 + quad * 4 + r) * RESS + col] = fast_silu(acc[mt][j][r]);
            }
    }

    // ---- phase 4: in-tile scan (2-way split over l)
    const int c = t & 127, hh = t >> 7;
    float pfx[16];
    float offl;
    {
        short8 sv0 = *(const short8*)&sbuf[c * STRS + hh * 16];
        short8 sv1 = *(const short8*)&sbuf[c * STRS + hh * 16 + 8];
        float run = 0.f;
        #pragma unroll
        for (int i = 0; i < 8; ++i) { run += bf2f(sv0[i]); pfx[i] = run; }
        #pragma unroll
        for (int i = 0; i < 8; ++i) { run += bf2f(sv1[i]); pfx[8 + i] = run; }
        totb[t] = run;
        __syncthreads();           // totb ready; all sbuf reads done
        offl = hh ? totb[c] : 0.f;
    }
    __syncthreads();               // totb consumed -> offb reuse OK

    // ---- phase 5: decoupled lookback (wave 0), W=64 lane-parallel windows
    if (w == 0) {
        float o0 = 0.f, o1 = 0.f;
        int p = tile - 1;
        while (p >= 0) {
            const int W = (p + 1 < 64) ? (p + 1) : 64;
            int fl = 0;
            if (lane < W)
                fl = __hip_atomic_load(&flags[cb + p - lane], __ATOMIC_ACQUIRE, __HIP_MEMORY_SCOPE_AGENT);
            const unsigned long long m2 = __ballot(fl == 2);
            const unsigned long long m0 = __ballot(fl == 0);  // lanes >= W read as 0
            const int k2 = m2 ? (__ffsll(m2) - 1) : 64;
            const int k0 = m0 ? (__ffsll(m0) - 1) : 64;
            const bool hp = (k2 < k0);
            const int usable = hp ? k2 : k0;
            for (int q = 0; q < usable; ++q) {
                const long pb = (cb + (p - q)) << 7;
                o0 += __hip_atomic_load(&agg[pb + lane], __ATOMIC_RELAXED, __HIP_MEMORY_SCOPE_AGENT);
                o1 += __hip_atomic_load(&agg[pb + 64 + lane], __ATOMIC_RELAXED, __HIP_MEMORY_SCOPE_AGENT);
            }
            if (hp) {
                const long pb = (cb + (p - usable)) << 7;
                o0 += __hip_atomic_load(&pref[pb + lane], __ATOMIC_RELAXED, __HIP_MEMORY_SCOPE_AGENT);
                o1 += __hip_atomic_load(&pref[pb + 64 + lane], __ATOMIC_RELAXED, __HIP_MEMORY_SCOPE_AGENT);
                break;
            }
            p -= usable;
            if (usable == 0) __builtin_amdgcn_s_sleep(8);
        }
        // publish inclusive prefix; release drains the wave's VMEM first
        const long mb = (cb + tile) << 7;
        __hip_atomic_store(&pref[mb + lane], o0 + aggb[lane], __ATOMIC_RELAXED, __HIP_MEMORY_SCOPE_AGENT);
        __hip_atomic_store(&pref[mb + 64 + lane], o1 + aggb[lane + 64], __ATOMIC_RELAXED, __HIP_MEMORY_SCOPE_AGENT);
        if (lane == 0)
            __hip_atomic_store(&flags[cb + tile], 2, __ATOMIC_RELEASE, __HIP_MEMORY_SCOPE_AGENT);
        offb[lane] = o0;
        offb[lane + 64] = o1;
    }
    __syncthreads();               // offb ready

    // ---- phase 6: gate -> ybf (overlays sbuf; sbuf reads finished)
    {
        const float off = offb[c] + offl;
        #pragma unroll
        for (int q = 0; q < 16; ++q)
            ybf[(hh * 16 + q) * STRC + c] =
                __float2bfloat16(resf[(hh * 16 + q) * RESS + c] * (off + pfx[q]));
    }
    __syncthreads();

    // ---- phase 7: out-proj MFMA (M=32, N=64, K=128) -> zbuf (=resf)
    {
        float* zbuf = resf;
        floatx4 acc[2] = {};
        const int n = w * 16 + lr;
        #pragma unroll
        for (int ks = 0; ks < 4; ++ks) {
            short8 bfr = *(const short8*)(wot + (n << 7) + ks * 32 + quad * 8);
            #pragma unroll
            for (int mt = 0; mt < 2; ++mt) {
                short8 afr = *(const short8*)&ybf[(mt * 16 + lr) * STRC + ks * 32 + quad * 8];
                acc[mt] = __builtin_amdgcn_mfma_f32_16x16x32_bf16(afr, bfr, acc[mt], 0, 0, 0);
            }
        }
        __syncthreads();
        #pragma unroll
        for (int mt = 0; mt < 2; ++mt)
            #pragma unroll
            for (int r = 0; r < 4; ++r)
                zbuf[(mt * 16 + quad * 4 + r) * 68 + n] = acc[mt][r];
    }
    __syncthreads();

    // ---- phase 8: residual + LayerNorm(64)
    {
        const float* zbuf = resf;
        const int d = t & 63;
        const int dg = t >> 6;
        const float g  = gamma[d];
        const float bt = beta[d];
        #pragma unroll 2
        for (int i = 0; i < 8; ++i) {
            int q = dg + 4 * i;
            float z = zbuf[q * 68 + d] + x[(base + l0 + q) * 64 + d];
            float zsum = z;
            #pragma unroll
            for (int off = 32; off > 0; off >>= 1) zsum += __shfl_xor(zsum, off);
            float mu = zsum * 0.015625f;
            float dz = z - mu;
            float vsum = dz * dz;
            #pragma unroll
            for (int off = 32; off > 0; off >>= 1) vsum += __shfl_xor(vsum, off);
            float inv = rsqrtf(vsum * 0.015625f + 1e-3f);
            out[(base + l0 + q) * 64 + d] = g * dz * inv + bt;
        }
    }
}

extern "C" void kernel_launch(void* const* d_in, const int* in_sizes, int n_in,
                              void* d_out, int out_size, void* d_ws, size_t ws_size,
                              hipStream_t stream) {
    const float* x      = (const float*)d_in[0];
    const float* W_in   = (const float*)d_in[1];
    const float* conv_w = (const float*)d_in[2];
    const float* conv_b = (const float*)d_in[3];
    const float* W_x    = (const float*)d_in[4];
    const float* W_dt   = (const float*)d_in[5];
    const float* b_dt   = (const float*)d_in[6];
    const float* W_out  = (const float*)d_in[7];
    const float* gamma  = (const float*)d_in[8];
    const float* beta   = (const float*)d_in[9];
    float* out = (float*)d_out;

    // workspace layout (bytes)
    float* agg   = (float*)d_ws;                                        // 3,538,944
    float* pref  = (float*)((char*)d_ws + 3538944);                     // 3,538,944
    int*   flags = (int*)((char*)d_ws + 7077888);                       //    27,648
    __hip_bfloat16* wti = (__hip_bfloat16*)((char*)d_ws + 8000000);     //    16,384
    __hip_bfloat16* wpt = (__hip_bfloat16*)((char*)d_ws + 8016384);     //    65,536
    __hip_bfloat16* wtr = (__hip_bfloat16*)((char*)d_ws + 8081920);     //    16,384
    __hip_bfloat16* wot = (__hip_bfloat16*)((char*)d_ws + 8098304);     //    16,384

    kW_w<<<1, 256, 0, stream>>>(W_in, W_x, W_dt, W_out, wti, wpt, wtr, wot, flags);
    dim3 grid(NT, 2);
    kF<<<grid, 256, 0, stream>>>(x, wti, wpt, wtr, wot, conv_w, conv_b, b_dt,
                                 gamma, beta, agg, pref, flags, out);
}